// Round 3
// baseline (161.294 us; speedup 1.0000x reference)
//
#include <hip/hip_runtime.h>

// L1 attention: out[b,i,j,h] = -0.125 * sum_d |q[b,i,h,d] - k[b,j,h,d]|
// B=2, T=512, H=8, D=64.  out (B,T,T,H) h innermost.
//
// No LDS. lane = j (k-row register-resident, 64 VGPR);
// wave = h (q-row address wave-uniform -> s_load to SGPRs).
// Inner loop is pure VALU: v_sub_f32 (SGPR,VGPR) + v_add_f32 with |abs|.
// Grid 8x32x2 blocks x 512 thr = 4096 waves = 4/SIMD, no barriers.

#define TDIM 512
#define HDIM 8
#define DDIM 64
#define JBLK 64     // j's per wave (= lanes)
#define IBLK 16     // i's per wave

__global__ __launch_bounds__(512, 4) void l1attn_kernel(
    const float* __restrict__ q, const float* __restrict__ k,
    float* __restrict__ out)
{
    const int t    = threadIdx.x;
    const int lane = t & 63;
    const int h    = __builtin_amdgcn_readfirstlane(t >> 6);  // wave-uniform
    const int j0   = blockIdx.x * JBLK;
    const int i0   = blockIdx.y * IBLK;
    const int b    = blockIdx.z;

    // ---- k row for this lane: k[b][j0+lane][h][0..63] -> 16 float4 in VGPRs ----
    const float* krow = k + (((size_t)(b * TDIM + j0 + lane)) * HDIM + h) * DDIM;
    float4 kr[16];
    #pragma unroll
    for (int c = 0; c < 16; ++c)
        kr[c] = *(const float4*)(krow + 4 * c);

    #pragma unroll 2
    for (int ii = 0; ii < IBLK; ++ii) {
        const int i = i0 + ii;
        // wave-uniform q row -> scalar loads
        const float* qrow = q + (((size_t)(b * TDIM + i)) * HDIM + h) * DDIM;

        float a0 = 0.f, a1 = 0.f, a2 = 0.f, a3 = 0.f;
        #pragma unroll
        for (int c = 0; c < 16; ++c) {
            float4 qv = *(const float4*)(qrow + 4 * c);
            a0 += fabsf(qv.x - kr[c].x);
            a1 += fabsf(qv.y - kr[c].y);
            a2 += fabsf(qv.z - kr[c].z);
            a3 += fabsf(qv.w - kr[c].w);
        }
        float acc = (a0 + a1) + (a2 + a3);

        // out[b][i][j0+lane][h]
        out[((size_t)(b * TDIM + i) * TDIM + (j0 + lane)) * HDIM + h] = acc * -0.125f;
    }
}

extern "C" void kernel_launch(void* const* d_in, const int* in_sizes, int n_in,
                              void* d_out, int out_size, void* d_ws, size_t ws_size,
                              hipStream_t stream) {
    const float* q = (const float*)d_in[0];
    const float* k = (const float*)d_in[1];
    float* out = (float*)d_out;
    const int B = in_sizes[0] / (TDIM * HDIM * DDIM);   // = 2
    dim3 grid(TDIM / JBLK, TDIM / IBLK, B);              // (8, 32, 2)
    l1attn_kernel<<<grid, 512, 0, stream>>>(q, k, out);
}

// Round 4
// 106.628 us; speedup vs baseline: 1.5127x; 1.5127x over previous
//
#include <hip/hip_runtime.h>

// L1 attention: out[b,i,j,h] = -0.125 * sum_d |q[b,i,h,d] - k[b,j,h,d]|
// B=2, T=512, H=8, D=64.  out (B,T,T,H), h innermost.
//
// Block 256 thr = 4 waves: tile = 16 i x 64 j x all 8 h (h looped).
// lane = j. k tile staged in LDS per h (stride 68 floats -> 2-way = free),
// prefetched into regs one h ahead (latency hidden under compute).
// q comes from the SCALAR path: wave-uniform row addresses -> s_load ->
// SGPR operands, so LDS only carries k (reused across R=4 i's in regs):
// LDS/VALU cycle ratio = 3.0*(1/4) = 0.75 -> VALU-bound.
// Output staged in LDS (plane stride 1025 -> 2-way both phases), then
// written out fully coalesced (each wave stores 1KB contiguous).

#define TDIM 512
#define HDIM 8
#define DDIM 64
#define HD   (HDIM * DDIM)      // 512
#define JT   64
#define IT   16
#define KSTR 68                  // ks row stride (floats)
#define OPL  1025                // outs h-plane stride (floats)

__global__ __launch_bounds__(256, 3) void l1attn_kernel(
    const float* __restrict__ q, const float* __restrict__ k,
    float* __restrict__ out)
{
    __shared__ float ks[JT * KSTR];          // 17408 B
    __shared__ float outs[HDIM * OPL];       // 32800 B

    const int t    = threadIdx.x;
    const int lane = t & 63;
    const int w    = __builtin_amdgcn_readfirstlane(t >> 6);   // wave id 0..3
    const int j0   = blockIdx.x * JT;
    const int i0   = blockIdx.y * IT;
    const int b    = blockIdx.z;

    // ---- staging geometry: thread t loads rows {t>>4 + 16v}, chunk t&15 ----
    const int srow = t >> 4;                 // 0..15
    const int sc   = t & 15;                 // 0..15
    const float* kbase = k + ((size_t)(b * TDIM + j0 + srow)) * HD + sc * 4;
    const int    soff  = srow * KSTR + sc * 4;

    // prefetch h = 0 into regs
    float4 kreg[4];
    #pragma unroll
    for (int v = 0; v < 4; ++v)
        kreg[v] = *(const float4*)(kbase + (size_t)v * 16 * HD + 0 * DDIM);

    for (int h = 0; h < 8; ++h) {
        __syncthreads();   // previous compute done reading ks
        #pragma unroll
        for (int v = 0; v < 4; ++v)
            *(float4*)&ks[soff + v * 16 * KSTR] = kreg[v];

        // issue next-h loads; latency hides under this h's compute
        float4 knext[4];
        if (h < 7) {
            #pragma unroll
            for (int v = 0; v < 4; ++v)
                knext[v] = *(const float4*)(kbase + (size_t)v * 16 * HD + (h + 1) * DDIM);
        }
        __syncthreads();   // ks ready

        // ---- compute: wave w handles i = i0 + 4w + r, r = 0..3 ----
        // q row addresses are wave-uniform -> scalar loads
        const float* qp = q + ((size_t)(b * TDIM + i0 + 4 * w)) * HD + (size_t)h * DDIM;

        float acc[4] = {0.f, 0.f, 0.f, 0.f};
        #pragma unroll 4
        for (int c = 0; c < 16; ++c) {
            float4 kv = *(const float4*)&ks[lane * KSTR + c * 4];
            #pragma unroll
            for (int r = 0; r < 4; ++r) {
                const float* qr = qp + r * HD + c * 4;
                acc[r] += fabsf(qr[0] - kv.x);
                acc[r] += fabsf(qr[1] - kv.y);
                acc[r] += fabsf(qr[2] - kv.z);
                acc[r] += fabsf(qr[3] - kv.w);
            }
        }

        #pragma unroll
        for (int r = 0; r < 4; ++r)
            outs[h * OPL + (w * 4 + r) * 64 + lane] = acc[r] * -0.125f;

        #pragma unroll
        for (int v = 0; v < 4; ++v)
            kreg[v] = knext[v];
    }

    __syncthreads();   // all outs written

    // ---- coalesced writeout: 8192 floats = 8 iters x 256 thr x float4 ----
    #pragma unroll
    for (int u = 0; u < 8; ++u) {
        int idx = u * 256 + t;
        int il  = idx >> 7;          // 0..15
        int rem = idx & 127;
        int j   = rem >> 1;          // 0..63
        int hh  = rem & 1;           // h-half
        float4 o;
        o.x = outs[(hh * 4 + 0) * OPL + il * 64 + j];
        o.y = outs[(hh * 4 + 1) * OPL + il * 64 + j];
        o.z = outs[(hh * 4 + 2) * OPL + il * 64 + j];
        o.w = outs[(hh * 4 + 3) * OPL + il * 64 + j];
        size_t goff = (((size_t)(b * TDIM + i0 + il)) * TDIM + (j0 + j)) * HDIM + hh * 4;
        *(float4*)(out + goff) = o;
    }
}

extern "C" void kernel_launch(void* const* d_in, const int* in_sizes, int n_in,
                              void* d_out, int out_size, void* d_ws, size_t ws_size,
                              hipStream_t stream) {
    const float* q = (const float*)d_in[0];
    const float* k = (const float*)d_in[1];
    float* out = (float*)d_out;
    const int B = in_sizes[0] / (TDIM * HD);   // = 2
    dim3 grid(TDIM / JT, TDIM / IT, B);         // (8, 32, 2)
    l1attn_kernel<<<grid, 256, 0, stream>>>(q, k, out);
}

// Round 5
// 94.863 us; speedup vs baseline: 1.7003x; 1.1240x over previous
//
#include <hip/hip_runtime.h>

// L1 attention: out[b,i,j,h] = -0.125 * sum_d |q[b,i,h,d] - k[b,j,h,d]|
// B=2, T=512, H=8, D=64.  out (B,T,T,H), h innermost.
//
// v5: no scalar loads, no per-h barriers.
//  - q tile (16 i x 8 h x 64 d, f32, 32 KB) staged in LDS ONCE; inner loop
//    reads it with wave-uniform ds_read_b128 (same-address broadcast = free).
//  - k register-resident: lane = j, 16 float4 per h, double-buffered (ka/kb),
//    next-h prefetched from global (L2-hot) under current-h compute.
//  - wave w owns i-locals {4w..4w+3}; 4 independent acc chains, 1 acc-add per
//    c step (abs-adds reduced as a tree first) -> no dependence stall.
//  - outs staged in LDS (plane stride 1025 -> conflict-free-ish) and written
//    out fully coalesced: every 64B line from one wave-instruction, once.

#define TDIM 512
#define HDIM 8
#define DDIM 64
#define HD   (HDIM * DDIM)      // 512
#define JT   64
#define IT   16
#define OPL  1025                // outs h-plane stride (floats)

__global__ __launch_bounds__(256, 2) void l1attn_kernel(
    const float* __restrict__ q, const float* __restrict__ k,
    float* __restrict__ out)
{
    __shared__ float qs[IT * HD];            // 32768 B
    __shared__ float outs[HDIM * OPL];       // 32800 B

    const int t    = threadIdx.x;
    const int lane = t & 63;
    const int w    = __builtin_amdgcn_readfirstlane(t >> 6);   // wave id 0..3
    const int j0   = blockIdx.x * JT;
    const int i0   = blockIdx.y * IT;
    const int b    = blockIdx.z;

    // ---- stage q tile once: 16 rows x 512 floats = 2048 float4, 8/thread ----
    #pragma unroll
    for (int v = 0; v < 8; ++v) {
        int chunk = v * 256 + t;
        int row   = chunk >> 7;              // 0..15
        int col4  = chunk & 127;             // 0..127
        *(float4*)&qs[row * HD + col4 * 4] =
            *(const float4*)(q + ((size_t)(b * TDIM + i0 + row)) * HD + col4 * 4);
    }
    __syncthreads();

    // ---- k row base for this lane ----
    const float* krow = k + ((size_t)(b * TDIM + j0 + lane)) * HD;

    float4 ka[16], kb[16];
    #pragma unroll
    for (int c = 0; c < 16; ++c) ka[c] = *(const float4*)(krow + 0 * DDIM + c * 4);

    const float* qw = &qs[(4 * w) * HD];     // wave's 4 q rows

#define PREF(DST, H) \
    { _Pragma("unroll") \
      for (int c = 0; c < 16; ++c) DST[c] = *(const float4*)(krow + (H) * DDIM + c * 4); }

#define BODY(KARR, H) \
    { float acc[4] = {0.f, 0.f, 0.f, 0.f}; \
      _Pragma("unroll") \
      for (int c = 0; c < 16; ++c) { \
        _Pragma("unroll") \
        for (int r = 0; r < 4; ++r) { \
          float4 qv = *(const float4*)&qw[r * HD + (H) * DDIM + c * 4]; \
          float d0 = qv.x - KARR[c].x, d1 = qv.y - KARR[c].y; \
          float d2 = qv.z - KARR[c].z, d3 = qv.w - KARR[c].w; \
          float s01 = fabsf(d0) + fabsf(d1); \
          float s23 = fabsf(d2) + fabsf(d3); \
          acc[r] += s01 + s23; \
        } \
      } \
      _Pragma("unroll") \
      for (int r = 0; r < 4; ++r) \
        outs[(H) * OPL + (4 * w + r) * 64 + lane] = acc[r] * -0.125f; }

    #pragma unroll
    for (int hp = 0; hp < 4; ++hp) {
        const int h0 = 2 * hp;
        PREF(kb, h0 + 1);
        BODY(ka, h0);
        if (hp < 3) PREF(ka, h0 + 2);
        BODY(kb, h0 + 1);
    }
#undef PREF
#undef BODY

    __syncthreads();   // all outs written

    // ---- coalesced writeout: 8192 floats = 8 iters x 256 thr x float4 ----
    #pragma unroll
    for (int u = 0; u < 8; ++u) {
        int idx = u * 256 + t;
        int il  = idx >> 7;          // 0..15
        int rem = idx & 127;
        int j   = rem >> 1;          // 0..63
        int hh  = rem & 1;           // h-half
        float4 o;
        o.x = outs[(hh * 4 + 0) * OPL + il * 64 + j];
        o.y = outs[(hh * 4 + 1) * OPL + il * 64 + j];
        o.z = outs[(hh * 4 + 2) * OPL + il * 64 + j];
        o.w = outs[(hh * 4 + 3) * OPL + il * 64 + j];
        size_t goff = (((size_t)(b * TDIM + i0 + il)) * TDIM + (j0 + j)) * HDIM + hh * 4;
        *(float4*)(out + goff) = o;
    }
}

extern "C" void kernel_launch(void* const* d_in, const int* in_sizes, int n_in,
                              void* d_out, int out_size, void* d_ws, size_t ws_size,
                              hipStream_t stream) {
    const float* q = (const float*)d_in[0];
    const float* k = (const float*)d_in[1];
    float* out = (float*)d_out;
    const int B = in_sizes[0] / (TDIM * HD);   // = 2
    dim3 grid(TDIM / JT, TDIM / IT, B);         // (8, 32, 2)
    l1attn_kernel<<<grid, 256, 0, stream>>>(q, k, out);
}